// Round 6
// baseline (862.755 us; speedup 1.0000x reference)
//
#include <hip/hip_runtime.h>
#include <math.h>

#define FEAT 512
#define HID  16
#define NCLS 40

// ---------------- CSR build: locality-binned ----------------
// Buckets of 512 consecutive dst nodes. Records packed: src (17b) | dstLocal (9b) << 17.
// CAPB = per-bucket capacity (mean ~16.3K for E=3.2M uniform, +16 sigma headroom).
#define CAPB 18432
#define BUFC 16   // LDS staging records per bucket = 64 B flush granularity

// bin_kernel: scatter edges into per-bucket regions with LDS 64B-group staging so
// global writes are coalesced full lines (fixes the 15x write amplification of the
// old fill_kernel's random 4B stores).
__global__ __launch_bounds__(256) void bin_kernel(const int* __restrict__ src,
                                                  const int* __restrict__ dst,
                                                  int* __restrict__ bcnt,
                                                  unsigned* __restrict__ bpack,
                                                  int E, int chunk) {
    __shared__ unsigned buf[256][BUFC];
    __shared__ int cl[256];
    int t = threadIdx.x;
    cl[t] = 0;
    __syncthreads();

    int e0 = blockIdx.x * chunk;
    int e1 = min(e0 + chunk, E);
    for (int e = e0; e < e1; e += 256) {
        int ee = e + t;
        int b = -1;
        unsigned rec = 0;
        if (ee < e1) {
            int d = dst[ee];
            int s = src[ee];
            b = d >> 9;
            rec = (unsigned)s | ((unsigned)(d & 511) << 17);
            int slot = atomicAdd(&cl[b], 1);
            if (slot < BUFC) { buf[b][slot] = rec; b = -1; }  // buffered
        }
        __syncthreads();
        // rare overflow: direct global append
        if (b >= 0) {
            int gp = atomicAdd(&bcnt[b], 1);
            if (gp < CAPB) bpack[(size_t)b * CAPB + gp] = rec;
        }
        // flush full 16-record (64B) groups, one thread per bucket
        {
            int c = cl[t];
            if (c >= BUFC) {
                int gp = atomicAdd(&bcnt[t], BUFC);
                if (gp + BUFC <= CAPB) {
                    unsigned* dp = bpack + (size_t)t * CAPB + gp;
#pragma unroll
                    for (int j = 0; j < BUFC; ++j) dp[j] = buf[t][j];
                }
                cl[t] = 0;  // records beyond BUFC went via direct path
            }
        }
        __syncthreads();
    }
    // drain partial buffers
    {
        int c = cl[t];
        if (c > 0) {
            if (c > BUFC) c = BUFC;
            int gp = atomicAdd(&bcnt[t], c);
            for (int j = 0; j < c; ++j)
                if (gp + j < CAPB) bpack[(size_t)t * CAPB + gp + j] = buf[t][j];
        }
    }
}

// bscan: exclusive scan of nbuck (<=256) bucket counts -> boff[0..nbuck]
__global__ void bscan_kernel(const int* __restrict__ bcnt, int* __restrict__ boff, int nbuck) {
    __shared__ int s[256];
    int t = threadIdx.x;
    int v = (t < nbuck) ? bcnt[t] : 0;
    s[t] = v;
    __syncthreads();
    for (int o = 1; o < 256; o <<= 1) {
        int add = (t >= o) ? s[t - o] : 0;
        __syncthreads();
        s[t] += add;
        __syncthreads();
    }
    if (t <= nbuck) boff[t] = (t > 0) ? s[t - 1] : 0;
}

// bucket_build: one block per bucket. Pass A: per-node degree via LDS atomics.
// LDS scan -> off/dinv (coalesced writes). Pass B: fill csr; stores land densely
// in this bucket's contiguous ~64KB csr window -> full-line writebacks.
__global__ __launch_bounds__(256) void bucket_build_kernel(const unsigned* __restrict__ bpack,
                                                           const int* __restrict__ boff,
                                                           int* __restrict__ off,
                                                           float* __restrict__ dinv,
                                                           int* __restrict__ csr,
                                                           int N, int E) {
    __shared__ int cnt[512];
    __shared__ int ptr[512];
    __shared__ int ss[256];
    int b = blockIdx.x;
    int t = threadIdx.x;
    int base = b << 9;
    int nn = min(512, N - base);

    cnt[t] = 0;
    cnt[t + 256] = 0;
    __syncthreads();

    int r0 = boff[b], r1 = boff[b + 1];
    int nrec = r1 - r0;
    const unsigned* bp = bpack + (size_t)b * CAPB;

    for (int j = t; j < nrec; j += 256) {
        unsigned rec = bp[j];
        atomicAdd(&cnt[rec >> 17], 1);
    }
    __syncthreads();

    // exclusive scan over 512 counts: 2 elems/thread + HS over 256 partials
    int a0 = cnt[2 * t], a1 = cnt[2 * t + 1];
    int tsum = a0 + a1;
    ss[t] = tsum;
    __syncthreads();
    for (int o = 1; o < 256; o <<= 1) {
        int add = (t >= o) ? ss[t - o] : 0;
        __syncthreads();
        ss[t] += add;
        __syncthreads();
    }
    int excl = (t > 0) ? ss[t - 1] : 0;

    int p0 = r0 + excl;
    int p1 = p0 + a0;
    ptr[2 * t] = p0;
    ptr[2 * t + 1] = p1;
    if (2 * t < nn) {
        off[base + 2 * t] = p0;
        dinv[base + 2 * t] = rsqrtf((float)a0 + 1.0f);
    }
    if (2 * t + 1 < nn) {
        off[base + 2 * t + 1] = p1;
        dinv[base + 2 * t + 1] = rsqrtf((float)a1 + 1.0f);
    }
    __syncthreads();

    // pass B: fill csr
    for (int j = t; j < nrec; j += 256) {
        unsigned rec = bp[j];
        int p = atomicAdd(&ptr[rec >> 17], 1);
        csr[p] = rec & 131071u;
    }

    if (b == (int)gridDim.x - 1 && t == 0) off[N] = E;
}

// ---------------- GEMM1: h1 = x @ W1  [N x 16] ----------------
// block = 256 threads, 16 rows per block. x tile + W1^T staged in LDS,
// both padded to stride 516 floats (=129 float4) for bank-conflict freedom:
// bank(516*r + k) = (4r + k) % 32 -> rows land in distinct bank groups.
__global__ __launch_bounds__(256) void gemm1_kernel(const float* __restrict__ x,
                                                    const float* __restrict__ W1,
                                                    float* __restrict__ h1, int N) {
    __shared__ float4 xt4[16 * 129];
    __shared__ float4 wt4[16 * 129];
    int t = threadIdx.x;

    // stage W1 transposed: W1[k][o] -> wt[o*516 + k]
    float* wt = (float*)wt4;
#pragma unroll
    for (int i = 0; i < 32; ++i) {
        int f = t + i * 256;           // 8192 elements
        int k = f >> 4, o = f & 15;
        wt[o * 516 + k] = W1[f];
    }

    int base = blockIdx.x * 16;        // N divisible by 16 (100000/16 = 6250)
    {
        const float4* xg = (const float4*)(x + (size_t)base * FEAT);
#pragma unroll
        for (int i = 0; i < 8; ++i) {
            int f = t + i * 256;       // 2048 float4
            int r = f >> 7, k4 = f & 127;
            xt4[r * 129 + k4] = xg[r * 128 + k4];
        }
    }
    __syncthreads();

    int r = t >> 4, o = t & 15;
    const float4* xr = (const float4*)((const float*)xt4 + r * 516);
    const float4* wr = (const float4*)((const float*)wt4 + o * 516);
    float acc = 0.f;
#pragma unroll 8
    for (int k = 0; k < 128; ++k) {
        float4 a = xr[k];
        float4 b = wr[k];
        acc += a.x * b.x + a.y * b.y + a.z * b.z + a.w * b.w;
    }
    h1[(size_t)(base + r) * HID + o] = acc;
}

// ---------------- Aggregation: out[i] = di*(sum_s dinv[s]*h[s] + di*h[i]) (+bias, relu)
// wave per node; lane = nb*16 + f : 4 neighbors x 16 features per iteration.
template <bool RELU>
__global__ __launch_bounds__(256) void agg_kernel(const float* __restrict__ h,
                                                  const float* __restrict__ dinv,
                                                  const int* __restrict__ off,
                                                  const int* __restrict__ csr,
                                                  const float* __restrict__ bias,
                                                  float* __restrict__ out, int N) {
    int wave = (blockIdx.x * 256 + threadIdx.x) >> 6;
    int lane = threadIdx.x & 63;
    if (wave >= N) return;
    int i = wave;
    int nb = lane >> 4, f = lane & 15;
    int o0 = off[i];
    int ne = off[i + 1] - o0;
    float acc = 0.f;
    for (int b = 0; b < ne; b += 4) {
        int j = b + nb;
        if (j < ne) {
            int s = csr[o0 + j];
            acc += dinv[s] * h[s * HID + f];
        }
    }
    acc += __shfl_xor(acc, 16);
    acc += __shfl_xor(acc, 32);
    float di = dinv[i];
    float v = di * (acc + di * h[i * HID + f]);
    if (bias) v += bias[f];
    if (RELU) v = fmaxf(v, 0.f);
    if (lane < 16) out[i * HID + f] = v;
}

// ---------------- Final: v = g @ W2 + b2, then log_softmax ----------------
__global__ __launch_bounds__(256) void final_kernel(const float* __restrict__ g,
                                                    const float* __restrict__ W2,
                                                    const float* __restrict__ b2,
                                                    float* __restrict__ out, int N) {
    __shared__ float w2s[HID * NCLS];
    __shared__ float b2s[NCLS];
    int t = threadIdx.x;
    for (int f = t; f < HID * NCLS; f += 256) w2s[f] = W2[f];
    if (t < NCLS) b2s[t] = b2[t];
    __syncthreads();

    int wave = (blockIdx.x * 256 + t) >> 6;
    int lane = t & 63;
    if (wave >= N) return;
    int i = wave;

    float acc = 0.f;
    float v = -1e30f;
    if (lane < NCLS) {
        acc = b2s[lane];
        const float* gr = g + (size_t)i * HID;
#pragma unroll
        for (int k = 0; k < HID; ++k) acc += gr[k] * w2s[k * NCLS + lane];
        v = acc;
    }
    // wave max over active lanes (inactive carry -1e30)
    for (int d = 32; d >= 1; d >>= 1) v = fmaxf(v, __shfl_xor(v, d));
    float e = (lane < NCLS) ? __expf(acc - v) : 0.f;
    float s = e;
    for (int d = 32; d >= 1; d >>= 1) s += __shfl_xor(s, d);
    if (lane < NCLS) out[(size_t)i * NCLS + lane] = acc - v - __logf(s);
}

// ---------------- launch ----------------

extern "C" void kernel_launch(void* const* d_in, const int* in_sizes, int n_in,
                              void* d_out, int out_size, void* d_ws, size_t ws_size,
                              hipStream_t stream) {
    const float* x  = (const float*)d_in[0];
    const int*   ei = (const int*)d_in[1];
    const float* W1 = (const float*)d_in[2];
    const float* b1 = (const float*)d_in[3];
    const float* W2 = (const float*)d_in[4];
    const float* b2 = (const float*)d_in[5];

    int N = in_sizes[0] / FEAT;   // 100000
    int E = in_sizes[1] / 2;      // 3200000
    const int* src = ei;
    const int* dst = ei + E;

    char* ws = (char*)d_ws;
    size_t p = 0;
    auto alloc = [&](size_t bytes) -> void* {
        void* r = ws + p;
        p = (p + bytes + 15) & ~(size_t)15;
        return r;
    };
    int*   off  = (int*)alloc((size_t)(N + 1) * 4);
    float* dinv = (float*)alloc((size_t)N * 4);
    int*   csr  = (int*)alloc((size_t)E * 4);
    float* h1   = (float*)alloc((size_t)N * HID * 4);
    float* a1   = (float*)alloc((size_t)N * HID * 4);
    float* g    = (float*)alloc((size_t)N * HID * 4);
    int*   bcnt = (int*)alloc((size_t)256 * 4);
    int*   boff = (int*)alloc((size_t)257 * 4);

    // bpack aliases h1/a1/g (19.2 MB contiguous): consumed by bucket_build
    // before gemm1 writes h1. nbuck*CAPB*4 = 196*18432*4 = 14.45 MB.
    unsigned* bpack = (unsigned*)h1;

    int nbuck = (N + 511) >> 9;       // 196 for N=100000
    int chunk = (E + 511) / 512;      // 512 bin blocks

    hipMemsetAsync(bcnt, 0, (size_t)256 * 4, stream);
    bin_kernel<<<512, 256, 0, stream>>>(src, dst, bcnt, bpack, E, chunk);
    bscan_kernel<<<1, 256, 0, stream>>>(bcnt, boff, nbuck);
    bucket_build_kernel<<<nbuck, 256, 0, stream>>>(bpack, boff, off, dinv, csr, N, E);

    gemm1_kernel<<<N / 16, 256, 0, stream>>>(x, W1, h1, N);
    agg_kernel<true><<<(N + 3) / 4, 256, 0, stream>>>(h1, dinv, off, csr, b1, a1, N);
    agg_kernel<false><<<(N + 3) / 4, 256, 0, stream>>>(a1, dinv, off, csr, nullptr, g, N);
    final_kernel<<<(N + 3) / 4, 256, 0, stream>>>(g, W2, b2, (float*)d_out, N);
}

// Round 11
// 618.134 us; speedup vs baseline: 1.3957x; 1.3957x over previous
//
#include <hip/hip_runtime.h>
#include <math.h>

#define FEAT 512
#define HID  16
#define NCLS 40

// ---------------- CSR build: two-phase, locality-binned ----------------
// Buckets of 512 consecutive dst nodes (196 buckets). Records packed:
// src (17b) | dstLocal (9b) << 17. CAPB = mean 16384 + 16 sigma.
#define CAPB  18432
#define CHUNK 4096
#define RPT   16          // records per thread = CHUNK/256
#define BPAD  16          // bcnt stride in ints (64B) -> one cache line per counter

// bin2: histogram -> exact global reservation (padded counters, 1 atomic per
// bucket per block) -> LDS counting sort -> coalesced bucket-contiguous copy-out.
// Fixes round-6 bin_kernel's same-line atomic storm + serial flushes.
__global__ __launch_bounds__(256) void bin2_kernel(const int* __restrict__ src,
                                                   const int* __restrict__ dst,
                                                   int* __restrict__ bcnt,
                                                   unsigned* __restrict__ bpack, int E) {
    __shared__ unsigned lsort[CHUNK];     // 16 KB packed records
    __shared__ int hist[256];             // histogram, then scatter cursor
    __shared__ int lstart[257];           // local exclusive offsets
    __shared__ int gbase[256];            // global base per bucket
    __shared__ int ss[256];               // scan scratch

    int t = threadIdx.x;
    int e0 = blockIdx.x * CHUNK;

    hist[t] = 0;
    __syncthreads();

    unsigned rec[RPT];
    int bkt[RPT];
#pragma unroll
    for (int i = 0; i < RPT; ++i) {
        int ee = e0 + i * 256 + t;
        bkt[i] = -1;
        if (ee < E) {
            int d = dst[ee];
            int s = src[ee];
            bkt[i] = d >> 9;
            rec[i] = (unsigned)s | ((unsigned)(d & 511) << 17);
            atomicAdd(&hist[bkt[i]], 1);
        }
    }
    __syncthreads();

    // exclusive scan over 256 bins
    int v = hist[t];
    ss[t] = v;
    __syncthreads();
    for (int o = 1; o < 256; o <<= 1) {
        int add = (t >= o) ? ss[t - o] : 0;
        __syncthreads();
        ss[t] += add;
        __syncthreads();
    }
    lstart[t] = ss[t] - v;
    if (t == 255) lstart[256] = ss[255];
    // exact reservation: one padded-line atomic per non-empty bucket
    if (v > 0) gbase[t] = atomicAdd(&bcnt[t * BPAD], v);
    hist[t] = 0;   // becomes scatter cursor
    __syncthreads();

    // counting-sort into packed LDS
#pragma unroll
    for (int i = 0; i < RPT; ++i) {
        if (bkt[i] >= 0) {
            int p = atomicAdd(&hist[bkt[i]], 1);
            lsort[lstart[bkt[i]] + p] = rec[i];
        }
    }
    __syncthreads();

    // coalesced copy-out: consecutive j -> consecutive global addresses per bucket run
    int nrec = lstart[256];
    for (int j = t; j < nrec; j += 256) {
        // largest b with lstart[b] <= j  (8-step binary search in LDS)
        int lo = 0, hi = 255;
        while (lo < hi) {
            int mid = (lo + hi + 1) >> 1;
            if (lstart[mid] <= j) lo = mid; else hi = mid - 1;
        }
        bpack[(size_t)lo * CAPB + gbase[lo] + (j - lstart[lo])] = lsort[j];
    }
}

// bscan: exclusive scan of nbuck (<=256) padded bucket counts -> boff[0..nbuck]
__global__ void bscan_kernel(const int* __restrict__ bcnt, int* __restrict__ boff, int nbuck) {
    __shared__ int s[256];
    int t = threadIdx.x;
    int v = (t < nbuck) ? bcnt[t * BPAD] : 0;
    s[t] = v;
    __syncthreads();
    for (int o = 1; o < 256; o <<= 1) {
        int add = (t >= o) ? s[t - o] : 0;
        __syncthreads();
        s[t] += add;
        __syncthreads();
    }
    if (t <= nbuck) boff[t] = (t > 0) ? s[t - 1] : 0;
}

// bucket_build: one block per bucket. Per-node degree via LDS atomics, LDS scan
// -> off/dinv (coalesced), then csr fill; stores land densely in the bucket's
// contiguous ~64KB csr window (single block -> single XCD -> full-line writebacks).
__global__ __launch_bounds__(256) void bucket_build_kernel(const unsigned* __restrict__ bpack,
                                                           const int* __restrict__ boff,
                                                           int* __restrict__ off,
                                                           float* __restrict__ dinv,
                                                           int* __restrict__ csr,
                                                           int N, int E) {
    __shared__ int cnt[512];
    __shared__ int ptr[512];
    __shared__ int ss[256];
    int b = blockIdx.x;
    int t = threadIdx.x;
    int base = b << 9;
    int nn = min(512, N - base);

    cnt[t] = 0;
    cnt[t + 256] = 0;
    __syncthreads();

    int r0 = boff[b], r1 = boff[b + 1];
    int nrec = r1 - r0;
    const unsigned* bp = bpack + (size_t)b * CAPB;

    for (int j = t; j < nrec; j += 256) {
        unsigned rec = bp[j];
        atomicAdd(&cnt[rec >> 17], 1);
    }
    __syncthreads();

    // exclusive scan over 512 counts: 2 elems/thread + HS over 256 partials
    int a0 = cnt[2 * t], a1 = cnt[2 * t + 1];
    int tsum = a0 + a1;
    ss[t] = tsum;
    __syncthreads();
    for (int o = 1; o < 256; o <<= 1) {
        int add = (t >= o) ? ss[t - o] : 0;
        __syncthreads();
        ss[t] += add;
        __syncthreads();
    }
    int excl = (t > 0) ? ss[t - 1] : 0;

    int p0 = r0 + excl;
    int p1 = p0 + a0;
    ptr[2 * t] = p0;
    ptr[2 * t + 1] = p1;
    if (2 * t < nn) {
        off[base + 2 * t] = p0;
        dinv[base + 2 * t] = rsqrtf((float)a0 + 1.0f);
    }
    if (2 * t + 1 < nn) {
        off[base + 2 * t + 1] = p1;
        dinv[base + 2 * t + 1] = rsqrtf((float)a1 + 1.0f);
    }
    __syncthreads();

    // fill csr
    for (int j = t; j < nrec; j += 256) {
        unsigned rec = bp[j];
        int p = atomicAdd(&ptr[rec >> 17], 1);
        csr[p] = rec & 131071u;
    }

    if (b == (int)gridDim.x - 1 && t == 0) off[N] = E;
}

// ---------------- GEMM1: h1 = x @ W1  [N x 16] ----------------
// block = 256 threads, 16 rows per block. x tile + W1^T staged in LDS,
// both padded to stride 516 floats (=129 float4) for bank-conflict freedom.
__global__ __launch_bounds__(256) void gemm1_kernel(const float* __restrict__ x,
                                                    const float* __restrict__ W1,
                                                    float* __restrict__ h1, int N) {
    __shared__ float4 xt4[16 * 129];
    __shared__ float4 wt4[16 * 129];
    int t = threadIdx.x;

    float* wt = (float*)wt4;
#pragma unroll
    for (int i = 0; i < 32; ++i) {
        int f = t + i * 256;           // 8192 elements
        int k = f >> 4, o = f & 15;
        wt[o * 516 + k] = W1[f];
    }

    int base = blockIdx.x * 16;        // N divisible by 16
    {
        const float4* xg = (const float4*)(x + (size_t)base * FEAT);
#pragma unroll
        for (int i = 0; i < 8; ++i) {
            int f = t + i * 256;       // 2048 float4
            int r = f >> 7, k4 = f & 127;
            xt4[r * 129 + k4] = xg[r * 128 + k4];
        }
    }
    __syncthreads();

    int r = t >> 4, o = t & 15;
    const float4* xr = (const float4*)((const float*)xt4 + r * 516);
    const float4* wr = (const float4*)((const float*)wt4 + o * 516);
    float acc = 0.f;
#pragma unroll 8
    for (int k = 0; k < 128; ++k) {
        float4 a = xr[k];
        float4 b = wr[k];
        acc += a.x * b.x + a.y * b.y + a.z * b.z + a.w * b.w;
    }
    h1[(size_t)(base + r) * HID + o] = acc;
}

// ---------------- Aggregation: out[i] = di*(sum_s dinv[s]*h[s] + di*h[i]) (+bias, relu)
template <bool RELU>
__global__ __launch_bounds__(256) void agg_kernel(const float* __restrict__ h,
                                                  const float* __restrict__ dinv,
                                                  const int* __restrict__ off,
                                                  const int* __restrict__ csr,
                                                  const float* __restrict__ bias,
                                                  float* __restrict__ out, int N) {
    int wave = (blockIdx.x * 256 + threadIdx.x) >> 6;
    int lane = threadIdx.x & 63;
    if (wave >= N) return;
    int i = wave;
    int nb = lane >> 4, f = lane & 15;
    int o0 = off[i];
    int ne = off[i + 1] - o0;
    float acc = 0.f;
    for (int b = 0; b < ne; b += 4) {
        int j = b + nb;
        if (j < ne) {
            int s = csr[o0 + j];
            acc += dinv[s] * h[s * HID + f];
        }
    }
    acc += __shfl_xor(acc, 16);
    acc += __shfl_xor(acc, 32);
    float di = dinv[i];
    float v = di * (acc + di * h[i * HID + f]);
    if (bias) v += bias[f];
    if (RELU) v = fmaxf(v, 0.f);
    if (lane < 16) out[i * HID + f] = v;
}

// ---------------- Final: v = g @ W2 + b2, then log_softmax ----------------
__global__ __launch_bounds__(256) void final_kernel(const float* __restrict__ g,
                                                    const float* __restrict__ W2,
                                                    const float* __restrict__ b2,
                                                    float* __restrict__ out, int N) {
    __shared__ float w2s[HID * NCLS];
    __shared__ float b2s[NCLS];
    int t = threadIdx.x;
    for (int f = t; f < HID * NCLS; f += 256) w2s[f] = W2[f];
    if (t < NCLS) b2s[t] = b2[t];
    __syncthreads();

    int wave = (blockIdx.x * 256 + t) >> 6;
    int lane = t & 63;
    if (wave >= N) return;
    int i = wave;

    float acc = 0.f;
    float v = -1e30f;
    if (lane < NCLS) {
        acc = b2s[lane];
        const float* gr = g + (size_t)i * HID;
#pragma unroll
        for (int k = 0; k < HID; ++k) acc += gr[k] * w2s[k * NCLS + lane];
        v = acc;
    }
    for (int d = 32; d >= 1; d >>= 1) v = fmaxf(v, __shfl_xor(v, d));
    float e = (lane < NCLS) ? __expf(acc - v) : 0.f;
    float s = e;
    for (int d = 32; d >= 1; d >>= 1) s += __shfl_xor(s, d);
    if (lane < NCLS) out[(size_t)i * NCLS + lane] = acc - v - __logf(s);
}

// ---------------- launch ----------------

extern "C" void kernel_launch(void* const* d_in, const int* in_sizes, int n_in,
                              void* d_out, int out_size, void* d_ws, size_t ws_size,
                              hipStream_t stream) {
    const float* x  = (const float*)d_in[0];
    const int*   ei = (const int*)d_in[1];
    const float* W1 = (const float*)d_in[2];
    const float* b1 = (const float*)d_in[3];
    const float* W2 = (const float*)d_in[4];
    const float* b2 = (const float*)d_in[5];

    int N = in_sizes[0] / FEAT;   // 100000
    int E = in_sizes[1] / 2;      // 3200000
    const int* src = ei;
    const int* dst = ei + E;

    char* ws = (char*)d_ws;
    size_t p = 0;
    auto alloc = [&](size_t bytes) -> void* {
        void* r = ws + p;
        p = (p + bytes + 15) & ~(size_t)15;
        return r;
    };
    int*   off  = (int*)alloc((size_t)(N + 1) * 4);
    float* dinv = (float*)alloc((size_t)N * 4);
    int*   csr  = (int*)alloc((size_t)E * 4);
    float* h1   = (float*)alloc((size_t)N * HID * 4);
    float* a1   = (float*)alloc((size_t)N * HID * 4);
    float* g    = (float*)alloc((size_t)N * HID * 4);
    int*   bcnt = (int*)alloc((size_t)256 * BPAD * 4);   // 64B-padded counters
    int*   boff = (int*)alloc((size_t)257 * 4);

    // bpack aliases h1/a1/g (19.2 MB contiguous): consumed by bucket_build
    // before gemm1 writes h1. nbuck*CAPB*4 = 196*18432*4 = 14.45 MB.
    unsigned* bpack = (unsigned*)h1;

    int nbuck = (N + 511) >> 9;               // 196
    int nbin  = (E + CHUNK - 1) / CHUNK;      // 782

    hipMemsetAsync(bcnt, 0, (size_t)256 * BPAD * 4, stream);
    bin2_kernel<<<nbin, 256, 0, stream>>>(src, dst, bcnt, bpack, E);
    bscan_kernel<<<1, 256, 0, stream>>>(bcnt, boff, nbuck);
    bucket_build_kernel<<<nbuck, 256, 0, stream>>>(bpack, boff, off, dinv, csr, N, E);

    gemm1_kernel<<<N / 16, 256, 0, stream>>>(x, W1, h1, N);
    agg_kernel<true><<<(N + 3) / 4, 256, 0, stream>>>(h1, dinv, off, csr, b1, a1, N);
    agg_kernel<false><<<(N + 3) / 4, 256, 0, stream>>>(a1, dinv, off, csr, nullptr, g, N);
    final_kernel<<<(N + 3) / 4, 256, 0, stream>>>(g, W2, b2, (float*)d_out, N);
}

// Round 13
// 531.163 us; speedup vs baseline: 1.6243x; 1.1637x over previous
//
#include <hip/hip_runtime.h>
#include <math.h>

#define FEAT 512
#define HID  16
#define NCLS 40

// ---------------- CSR build: two-phase, locality-binned ----------------
// Buckets of 512 consecutive dst nodes (196 buckets). Records packed:
// src (17b) | dstLocal (9b) << 17. CAPB = mean 16384 + 16 sigma.
#define CAPB  18432
#define CHUNK 4096
#define RPT   16          // records per thread = CHUNK/256
#define BPAD  16          // bcnt stride in ints (64B) -> one cache line per counter

// bin2: histogram -> exact global reservation (padded counters, 1 atomic per
// bucket per block) -> LDS counting sort -> coalesced bucket-contiguous copy-out.
__global__ __launch_bounds__(256) void bin2_kernel(const int* __restrict__ src,
                                                   const int* __restrict__ dst,
                                                   int* __restrict__ bcnt,
                                                   unsigned* __restrict__ bpack, int E) {
    __shared__ unsigned lsort[CHUNK];     // 16 KB packed records
    __shared__ int hist[256];             // histogram, then scatter cursor
    __shared__ int lstart[257];           // local exclusive offsets
    __shared__ int gbase[256];            // global base per bucket
    __shared__ int ss[256];               // scan scratch

    int t = threadIdx.x;
    int e0 = blockIdx.x * CHUNK;

    hist[t] = 0;
    __syncthreads();

    unsigned rec[RPT];
    int bkt[RPT];
#pragma unroll
    for (int i = 0; i < RPT; ++i) {
        int ee = e0 + i * 256 + t;
        bkt[i] = -1;
        if (ee < E) {
            int d = dst[ee];
            int s = src[ee];
            bkt[i] = d >> 9;
            rec[i] = (unsigned)s | ((unsigned)(d & 511) << 17);
            atomicAdd(&hist[bkt[i]], 1);
        }
    }
    __syncthreads();

    // exclusive scan over 256 bins
    int v = hist[t];
    ss[t] = v;
    __syncthreads();
    for (int o = 1; o < 256; o <<= 1) {
        int add = (t >= o) ? ss[t - o] : 0;
        __syncthreads();
        ss[t] += add;
        __syncthreads();
    }
    lstart[t] = ss[t] - v;
    if (t == 255) lstart[256] = ss[255];
    // exact reservation: one padded-line atomic per non-empty bucket
    if (v > 0) gbase[t] = atomicAdd(&bcnt[t * BPAD], v);
    hist[t] = 0;   // becomes scatter cursor
    __syncthreads();

    // counting-sort into packed LDS
#pragma unroll
    for (int i = 0; i < RPT; ++i) {
        if (bkt[i] >= 0) {
            int p = atomicAdd(&hist[bkt[i]], 1);
            lsort[lstart[bkt[i]] + p] = rec[i];
        }
    }
    __syncthreads();

    // coalesced copy-out: consecutive j -> consecutive global addresses per bucket run
    int nrec = lstart[256];
    for (int j = t; j < nrec; j += 256) {
        // largest b with lstart[b] <= j  (8-step binary search in LDS)
        int lo = 0, hi = 255;
        while (lo < hi) {
            int mid = (lo + hi + 1) >> 1;
            if (lstart[mid] <= j) lo = mid; else hi = mid - 1;
        }
        bpack[(size_t)lo * CAPB + gbase[lo] + (j - lstart[lo])] = lsort[j];
    }
}

// bscan: exclusive scan of nbuck (<=256) padded bucket counts -> boff[0..nbuck]
__global__ void bscan_kernel(const int* __restrict__ bcnt, int* __restrict__ boff, int nbuck) {
    __shared__ int s[256];
    int t = threadIdx.x;
    int v = (t < nbuck) ? bcnt[t * BPAD] : 0;
    s[t] = v;
    __syncthreads();
    for (int o = 1; o < 256; o <<= 1) {
        int add = (t >= o) ? s[t - o] : 0;
        __syncthreads();
        s[t] += add;
        __syncthreads();
    }
    if (t <= nbuck) boff[t] = (t > 0) ? s[t - 1] : 0;
}

// bucket_build: one block per bucket. Per-node degree via LDS atomics, LDS scan
// -> off/dinv (coalesced), then csr fill into the bucket's contiguous window.
__global__ __launch_bounds__(256) void bucket_build_kernel(const unsigned* __restrict__ bpack,
                                                           const int* __restrict__ boff,
                                                           int* __restrict__ off,
                                                           float* __restrict__ dinv,
                                                           int* __restrict__ csr,
                                                           int N, int E) {
    __shared__ int cnt[512];
    __shared__ int ptr[512];
    __shared__ int ss[256];
    int b = blockIdx.x;
    int t = threadIdx.x;
    int base = b << 9;
    int nn = min(512, N - base);

    cnt[t] = 0;
    cnt[t + 256] = 0;
    __syncthreads();

    int r0 = boff[b], r1 = boff[b + 1];
    int nrec = r1 - r0;
    const unsigned* bp = bpack + (size_t)b * CAPB;

    for (int j = t; j < nrec; j += 256) {
        unsigned rec = bp[j];
        atomicAdd(&cnt[rec >> 17], 1);
    }
    __syncthreads();

    // exclusive scan over 512 counts: 2 elems/thread + HS over 256 partials
    int a0 = cnt[2 * t], a1 = cnt[2 * t + 1];
    int tsum = a0 + a1;
    ss[t] = tsum;
    __syncthreads();
    for (int o = 1; o < 256; o <<= 1) {
        int add = (t >= o) ? ss[t - o] : 0;
        __syncthreads();
        ss[t] += add;
        __syncthreads();
    }
    int excl = (t > 0) ? ss[t - 1] : 0;

    int p0 = r0 + excl;
    int p1 = p0 + a0;
    ptr[2 * t] = p0;
    ptr[2 * t + 1] = p1;
    if (2 * t < nn) {
        off[base + 2 * t] = p0;
        dinv[base + 2 * t] = rsqrtf((float)a0 + 1.0f);
    }
    if (2 * t + 1 < nn) {
        off[base + 2 * t + 1] = p1;
        dinv[base + 2 * t + 1] = rsqrtf((float)a1 + 1.0f);
    }
    __syncthreads();

    // fill csr
    for (int j = t; j < nrec; j += 256) {
        unsigned rec = bp[j];
        int p = atomicAdd(&ptr[rec >> 17], 1);
        csr[p] = rec & 131071u;
    }

    if (b == (int)gridDim.x - 1 && t == 0) off[N] = E;
}

// ---------------- GEMM1: h1 = x @ W1  [N x 16] ----------------
__global__ __launch_bounds__(256) void gemm1_kernel(const float* __restrict__ x,
                                                    const float* __restrict__ W1,
                                                    float* __restrict__ h1, int N) {
    __shared__ float4 xt4[16 * 129];
    __shared__ float4 wt4[16 * 129];
    int t = threadIdx.x;

    float* wt = (float*)wt4;
#pragma unroll
    for (int i = 0; i < 32; ++i) {
        int f = t + i * 256;           // 8192 elements
        int k = f >> 4, o = f & 15;
        wt[o * 516 + k] = W1[f];
    }

    int base = blockIdx.x * 16;        // N divisible by 16
    {
        const float4* xg = (const float4*)(x + (size_t)base * FEAT);
#pragma unroll
        for (int i = 0; i < 8; ++i) {
            int f = t + i * 256;       // 2048 float4
            int r = f >> 7, k4 = f & 127;
            xt4[r * 129 + k4] = xg[r * 128 + k4];
        }
    }
    __syncthreads();

    int r = t >> 4, o = t & 15;
    const float4* xr = (const float4*)((const float*)xt4 + r * 516);
    const float4* wr = (const float4*)((const float*)wt4 + o * 516);
    float acc = 0.f;
#pragma unroll 8
    for (int k = 0; k < 128; ++k) {
        float4 a = xr[k];
        float4 b = wr[k];
        acc += a.x * b.x + a.y * b.y + a.z * b.z + a.w * b.w;
    }
    h1[(size_t)(base + r) * HID + o] = acc;
}

// ---------------- Aggregation pass 1 (+bias,+relu) ----------------
// wave per node; lane = nb*4 + q : 16 neighbors x float4 per iteration (4x the
// gather ILP of the old 4x16-scalar layout; ~2 iterations at mean deg 32).
// After the xor-butterfly every lane holds the full sum for its feature quarter.
__global__ __launch_bounds__(256) void agg1_kernel(const float* __restrict__ h,
                                                   const float* __restrict__ dinv,
                                                   const int* __restrict__ off,
                                                   const int* __restrict__ csr,
                                                   const float* __restrict__ bias,
                                                   float* __restrict__ out, int N) {
    int wave = (blockIdx.x * 256 + threadIdx.x) >> 6;
    int lane = threadIdx.x & 63;
    if (wave >= N) return;
    int i = wave;
    int nb = lane >> 2, q = lane & 3;
    int o0 = off[i];
    int ne = off[i + 1] - o0;
    float4 acc = {0.f, 0.f, 0.f, 0.f};
    for (int b = 0; b < ne; b += 16) {
        int j = b + nb;
        if (j < ne) {
            int s = csr[o0 + j];
            float w = dinv[s];
            float4 hv = *(const float4*)(h + (size_t)s * HID + q * 4);
            acc.x += w * hv.x; acc.y += w * hv.y;
            acc.z += w * hv.z; acc.w += w * hv.w;
        }
    }
    for (int d = 4; d <= 32; d <<= 1) {
        acc.x += __shfl_xor(acc.x, d);
        acc.y += __shfl_xor(acc.y, d);
        acc.z += __shfl_xor(acc.z, d);
        acc.w += __shfl_xor(acc.w, d);
    }
    if (lane < 4) {
        float di = dinv[i];
        float4 hs = *(const float4*)(h + (size_t)i * HID + q * 4);
        float4 b4 = *(const float4*)(bias + q * 4);
        float4 v;
        v.x = fmaxf(di * (acc.x + di * hs.x) + b4.x, 0.f);
        v.y = fmaxf(di * (acc.y + di * hs.y) + b4.y, 0.f);
        v.z = fmaxf(di * (acc.z + di * hs.z) + b4.z, 0.f);
        v.w = fmaxf(di * (acc.w + di * hs.w) + b4.w, 0.f);
        *(float4*)(out + (size_t)i * HID + q * 4) = v;
    }
}

// ---------------- Fused pass 2: agg -> W2 matvec -> log_softmax ----------------
// Same gather structure as agg1; the g-row never touches memory: after the
// butterfly each lane holds its quarter, 16 __shfl broadcasts feed the 40-class
// matvec, then in-wave max/sum for log_softmax. Kills final_kernel + g traffic.
__global__ __launch_bounds__(256) void agg2_final_kernel(const float* __restrict__ h,
                                                         const float* __restrict__ dinv,
                                                         const int* __restrict__ off,
                                                         const int* __restrict__ csr,
                                                         const float* __restrict__ W2,
                                                         const float* __restrict__ b2,
                                                         float* __restrict__ out, int N) {
    __shared__ float w2s[HID * NCLS];
    __shared__ float b2s[NCLS];
    int t = threadIdx.x;
    for (int f = t; f < HID * NCLS; f += 256) w2s[f] = W2[f];
    if (t < NCLS) b2s[t] = b2[t];
    __syncthreads();

    int wave = (blockIdx.x * 256 + t) >> 6;
    int lane = t & 63;
    if (wave >= N) return;
    int i = wave;
    int nb = lane >> 2, q = lane & 3;
    int o0 = off[i];
    int ne = off[i + 1] - o0;
    float4 acc = {0.f, 0.f, 0.f, 0.f};
    for (int b = 0; b < ne; b += 16) {
        int j = b + nb;
        if (j < ne) {
            int s = csr[o0 + j];
            float w = dinv[s];
            float4 hv = *(const float4*)(h + (size_t)s * HID + q * 4);
            acc.x += w * hv.x; acc.y += w * hv.y;
            acc.z += w * hv.z; acc.w += w * hv.w;
        }
    }
    for (int d = 4; d <= 32; d <<= 1) {
        acc.x += __shfl_xor(acc.x, d);
        acc.y += __shfl_xor(acc.y, d);
        acc.z += __shfl_xor(acc.z, d);
        acc.w += __shfl_xor(acc.w, d);
    }
    // g quarter on every lane (for its q)
    float di = dinv[i];
    float4 hs = *(const float4*)(h + (size_t)i * HID + q * 4);
    float4 g4;
    g4.x = di * (acc.x + di * hs.x);
    g4.y = di * (acc.y + di * hs.y);
    g4.z = di * (acc.z + di * hs.z);
    g4.w = di * (acc.w + di * hs.w);

    bool act = lane < NCLS;
    int lw = act ? lane : 0;
    float accv = 0.f;
#pragma unroll
    for (int k = 0; k < HID; ++k) {
        float comp = ((k & 3) == 0) ? g4.x : ((k & 3) == 1) ? g4.y
                   : ((k & 3) == 2) ? g4.z : g4.w;
        float gb = __shfl(comp, k >> 2);   // all lanes participate
        accv += gb * w2s[k * NCLS + lw];
    }
    accv += b2s[lw];
    float v = act ? accv : -1e30f;
    for (int d = 32; d >= 1; d >>= 1) v = fmaxf(v, __shfl_xor(v, d));
    float e = act ? __expf(accv - v) : 0.f;
    float s = e;
    for (int d = 32; d >= 1; d >>= 1) s += __shfl_xor(s, d);
    if (act) out[(size_t)i * NCLS + lane] = accv - v - __logf(s);
}

// ---------------- launch ----------------

extern "C" void kernel_launch(void* const* d_in, const int* in_sizes, int n_in,
                              void* d_out, int out_size, void* d_ws, size_t ws_size,
                              hipStream_t stream) {
    const float* x  = (const float*)d_in[0];
    const int*   ei = (const int*)d_in[1];
    const float* W1 = (const float*)d_in[2];
    const float* b1 = (const float*)d_in[3];
    const float* W2 = (const float*)d_in[4];
    const float* b2 = (const float*)d_in[5];

    int N = in_sizes[0] / FEAT;   // 100000
    int E = in_sizes[1] / 2;      // 3200000
    const int* src = ei;
    const int* dst = ei + E;

    char* ws = (char*)d_ws;
    size_t p = 0;
    auto alloc = [&](size_t bytes) -> void* {
        void* r = ws + p;
        p = (p + bytes + 15) & ~(size_t)15;
        return r;
    };
    int*   off  = (int*)alloc((size_t)(N + 1) * 4);
    float* dinv = (float*)alloc((size_t)N * 4);
    int*   csr  = (int*)alloc((size_t)E * 4);
    float* h1   = (float*)alloc((size_t)N * HID * 4);
    float* a1   = (float*)alloc((size_t)N * HID * 4);
    float* pad  = (float*)alloc((size_t)N * HID * 4);  // keeps bpack alias in-bounds
    int*   bcnt = (int*)alloc((size_t)256 * BPAD * 4); // 64B-padded counters
    int*   boff = (int*)alloc((size_t)257 * 4);
    (void)pad;

    // bpack aliases h1/a1/pad (19.2 MB contiguous): consumed by bucket_build
    // before gemm1 writes h1. nbuck*CAPB*4 = 196*18432*4 = 14.45 MB.
    unsigned* bpack = (unsigned*)h1;

    int nbuck = (N + 511) >> 9;               // 196
    int nbin  = (E + CHUNK - 1) / CHUNK;      // 782

    hipMemsetAsync(bcnt, 0, (size_t)256 * BPAD * 4, stream);
    bin2_kernel<<<nbin, 256, 0, stream>>>(src, dst, bcnt, bpack, E);
    bscan_kernel<<<1, 256, 0, stream>>>(bcnt, boff, nbuck);
    bucket_build_kernel<<<nbuck, 256, 0, stream>>>(bpack, boff, off, dinv, csr, N, E);

    gemm1_kernel<<<N / 16, 256, 0, stream>>>(x, W1, h1, N);
    agg1_kernel<<<(N + 3) / 4, 256, 0, stream>>>(h1, dinv, off, csr, b1, a1, N);
    agg2_final_kernel<<<(N + 3) / 4, 256, 0, stream>>>(a1, dinv, off, csr, W2, b2,
                                                       (float*)d_out, N);
}

// Round 14
// 522.241 us; speedup vs baseline: 1.6520x; 1.0171x over previous
//
#include <hip/hip_runtime.h>
#include <math.h>

#define FEAT 512
#define HID  16
#define NCLS 40

// ---------------- CSR build: two-phase, locality-binned ----------------
#define CAPB  18432
#define CHUNK 4096
#define RPT   16          // records per thread = CHUNK/256
#define BPAD  16          // bcnt stride in ints (64B) -> one cache line per counter

__global__ __launch_bounds__(256) void bin2_kernel(const int* __restrict__ src,
                                                   const int* __restrict__ dst,
                                                   int* __restrict__ bcnt,
                                                   unsigned* __restrict__ bpack, int E) {
    __shared__ unsigned lsort[CHUNK];     // 16 KB packed records
    __shared__ int hist[256];             // histogram, then scatter cursor
    __shared__ int lstart[257];           // local exclusive offsets
    __shared__ int gbase[256];            // global base per bucket
    __shared__ int ss[256];               // scan scratch

    int t = threadIdx.x;
    int e0 = blockIdx.x * CHUNK;

    hist[t] = 0;
    __syncthreads();

    unsigned rec[RPT];
    int bkt[RPT];
#pragma unroll
    for (int i = 0; i < RPT; ++i) {
        int ee = e0 + i * 256 + t;
        bkt[i] = -1;
        if (ee < E) {
            int d = dst[ee];
            int s = src[ee];
            bkt[i] = d >> 9;
            rec[i] = (unsigned)s | ((unsigned)(d & 511) << 17);
            atomicAdd(&hist[bkt[i]], 1);
        }
    }
    __syncthreads();

    int v = hist[t];
    ss[t] = v;
    __syncthreads();
    for (int o = 1; o < 256; o <<= 1) {
        int add = (t >= o) ? ss[t - o] : 0;
        __syncthreads();
        ss[t] += add;
        __syncthreads();
    }
    lstart[t] = ss[t] - v;
    if (t == 255) lstart[256] = ss[255];
    if (v > 0) gbase[t] = atomicAdd(&bcnt[t * BPAD], v);
    hist[t] = 0;
    __syncthreads();

#pragma unroll
    for (int i = 0; i < RPT; ++i) {
        if (bkt[i] >= 0) {
            int p = atomicAdd(&hist[bkt[i]], 1);
            lsort[lstart[bkt[i]] + p] = rec[i];
        }
    }
    __syncthreads();

    int nrec = lstart[256];
    for (int j = t; j < nrec; j += 256) {
        int lo = 0, hi = 255;
        while (lo < hi) {
            int mid = (lo + hi + 1) >> 1;
            if (lstart[mid] <= j) lo = mid; else hi = mid - 1;
        }
        bpack[(size_t)lo * CAPB + gbase[lo] + (j - lstart[lo])] = lsort[j];
    }
}

__global__ void bscan_kernel(const int* __restrict__ bcnt, int* __restrict__ boff, int nbuck) {
    __shared__ int s[256];
    int t = threadIdx.x;
    int v = (t < nbuck) ? bcnt[t * BPAD] : 0;
    s[t] = v;
    __syncthreads();
    for (int o = 1; o < 256; o <<= 1) {
        int add = (t >= o) ? s[t - o] : 0;
        __syncthreads();
        s[t] += add;
        __syncthreads();
    }
    if (t <= nbuck) boff[t] = (t > 0) ? s[t - 1] : 0;
}

__global__ __launch_bounds__(256) void bucket_build_kernel(const unsigned* __restrict__ bpack,
                                                           const int* __restrict__ boff,
                                                           int* __restrict__ off,
                                                           float* __restrict__ dinv,
                                                           int* __restrict__ csr,
                                                           int N, int E) {
    __shared__ int cnt[512];
    __shared__ int ptr[512];
    __shared__ int ss[256];
    int b = blockIdx.x;
    int t = threadIdx.x;
    int base = b << 9;
    int nn = min(512, N - base);

    cnt[t] = 0;
    cnt[t + 256] = 0;
    __syncthreads();

    int r0 = boff[b], r1 = boff[b + 1];
    int nrec = r1 - r0;
    const unsigned* bp = bpack + (size_t)b * CAPB;

    for (int j = t; j < nrec; j += 256) {
        unsigned rec = bp[j];
        atomicAdd(&cnt[rec >> 17], 1);
    }
    __syncthreads();

    int a0 = cnt[2 * t], a1 = cnt[2 * t + 1];
    int tsum = a0 + a1;
    ss[t] = tsum;
    __syncthreads();
    for (int o = 1; o < 256; o <<= 1) {
        int add = (t >= o) ? ss[t - o] : 0;
        __syncthreads();
        ss[t] += add;
        __syncthreads();
    }
    int excl = (t > 0) ? ss[t - 1] : 0;

    int p0 = r0 + excl;
    int p1 = p0 + a0;
    ptr[2 * t] = p0;
    ptr[2 * t + 1] = p1;
    if (2 * t < nn) {
        off[base + 2 * t] = p0;
        dinv[base + 2 * t] = rsqrtf((float)a0 + 1.0f);
    }
    if (2 * t + 1 < nn) {
        off[base + 2 * t + 1] = p1;
        dinv[base + 2 * t + 1] = rsqrtf((float)a1 + 1.0f);
    }
    __syncthreads();

    for (int j = t; j < nrec; j += 256) {
        unsigned rec = bp[j];
        int p = atomicAdd(&ptr[rec >> 17], 1);
        csr[p] = rec & 131071u;
    }

    if (b == (int)gridDim.x - 1 && t == 0) off[N] = E;
}

// ---------------- GEMM1: h1s = dinv * (x @ W1)  [N x 16], pre-scaled ----------------
// Pre-scaling by dinv[row] here removes the per-edge dinv gather from both agg
// passes (one fewer dependent random load per neighbor on the latency chain).
__global__ __launch_bounds__(256) void gemm1_kernel(const float* __restrict__ x,
                                                    const float* __restrict__ W1,
                                                    const float* __restrict__ dinv,
                                                    float* __restrict__ h1, int N) {
    __shared__ float4 xt4[16 * 129];
    __shared__ float4 wt4[16 * 129];
    int t = threadIdx.x;

    float* wt = (float*)wt4;
#pragma unroll
    for (int i = 0; i < 32; ++i) {
        int f = t + i * 256;           // 8192 elements
        int k = f >> 4, o = f & 15;
        wt[o * 516 + k] = W1[f];
    }

    int base = blockIdx.x * 16;        // N divisible by 16
    {
        const float4* xg = (const float4*)(x + (size_t)base * FEAT);
#pragma unroll
        for (int i = 0; i < 8; ++i) {
            int f = t + i * 256;       // 2048 float4
            int r = f >> 7, k4 = f & 127;
            xt4[r * 129 + k4] = xg[r * 128 + k4];
        }
    }
    __syncthreads();

    int r = t >> 4, o = t & 15;
    const float4* xr = (const float4*)((const float*)xt4 + r * 516);
    const float4* wr = (const float4*)((const float*)wt4 + o * 516);
    float acc = 0.f;
#pragma unroll 8
    for (int k = 0; k < 128; ++k) {
        float4 a = xr[k];
        float4 b = wr[k];
        acc += a.x * b.x + a.y * b.y + a.z * b.z + a.w * b.w;
    }
    h1[(size_t)(base + r) * HID + o] = acc * dinv[base + r];
}

// ---------------- Aggregation pass 1 (+bias,+relu), pre-scaled rows ----------------
// Input h = h1s (rows pre-scaled by dinv[src]). out[i] = di*(sum_nbr h[s] + h[i]) + b,
// relu, then stored PRE-SCALED for pass 2: a1s[i] = di * relu(...).
// Inner loop: single 16B gather per neighbor (dinv gather eliminated).
__global__ __launch_bounds__(256) void agg1_kernel(const float* __restrict__ h,
                                                   const float* __restrict__ dinv,
                                                   const int* __restrict__ off,
                                                   const int* __restrict__ csr,
                                                   const float* __restrict__ bias,
                                                   float* __restrict__ out, int N) {
    int wave = (blockIdx.x * 256 + threadIdx.x) >> 6;
    int lane = threadIdx.x & 63;
    if (wave >= N) return;
    int i = wave;
    int nb = lane >> 2, q = lane & 3;
    int o0 = off[i];
    int ne = off[i + 1] - o0;
    float4 acc = {0.f, 0.f, 0.f, 0.f};
    for (int b = 0; b < ne; b += 16) {
        int j = b + nb;
        if (j < ne) {
            int s = csr[o0 + j];
            float4 hv = *(const float4*)(h + (size_t)s * HID + q * 4);
            acc.x += hv.x; acc.y += hv.y;
            acc.z += hv.z; acc.w += hv.w;
        }
    }
    for (int d = 4; d <= 32; d <<= 1) {
        acc.x += __shfl_xor(acc.x, d);
        acc.y += __shfl_xor(acc.y, d);
        acc.z += __shfl_xor(acc.z, d);
        acc.w += __shfl_xor(acc.w, d);
    }
    if (lane < 4) {
        float di = dinv[i];
        float4 hs = *(const float4*)(h + (size_t)i * HID + q * 4);  // = di*h1[i]
        float4 b4 = *(const float4*)(bias + q * 4);
        float4 v;
        v.x = di * fmaxf(di * (acc.x + hs.x) + b4.x, 0.f);
        v.y = di * fmaxf(di * (acc.y + hs.y) + b4.y, 0.f);
        v.z = di * fmaxf(di * (acc.z + hs.z) + b4.z, 0.f);
        v.w = di * fmaxf(di * (acc.w + hs.w) + b4.w, 0.f);
        *(float4*)(out + (size_t)i * HID + q * 4) = v;
    }
}

// ---------------- Fused pass 2: agg (pre-scaled) -> W2 matvec -> log_softmax ----------------
__global__ __launch_bounds__(256) void agg2_final_kernel(const float* __restrict__ h,
                                                         const float* __restrict__ dinv,
                                                         const int* __restrict__ off,
                                                         const int* __restrict__ csr,
                                                         const float* __restrict__ W2,
                                                         const float* __restrict__ b2,
                                                         float* __restrict__ out, int N) {
    __shared__ float w2s[HID * NCLS];
    __shared__ float b2s[NCLS];
    int t = threadIdx.x;
    for (int f = t; f < HID * NCLS; f += 256) w2s[f] = W2[f];
    if (t < NCLS) b2s[t] = b2[t];
    __syncthreads();

    int wave = (blockIdx.x * 256 + t) >> 6;
    int lane = t & 63;
    if (wave >= N) return;
    int i = wave;
    int nb = lane >> 2, q = lane & 3;
    int o0 = off[i];
    int ne = off[i + 1] - o0;
    float4 acc = {0.f, 0.f, 0.f, 0.f};
    for (int b = 0; b < ne; b += 16) {
        int j = b + nb;
        if (j < ne) {
            int s = csr[o0 + j];
            float4 hv = *(const float4*)(h + (size_t)s * HID + q * 4);
            acc.x += hv.x; acc.y += hv.y;
            acc.z += hv.z; acc.w += hv.w;
        }
    }
    for (int d = 4; d <= 32; d <<= 1) {
        acc.x += __shfl_xor(acc.x, d);
        acc.y += __shfl_xor(acc.y, d);
        acc.z += __shfl_xor(acc.z, d);
        acc.w += __shfl_xor(acc.w, d);
    }
    // g quarter on every lane: g = di*(sum_nbr a1s[s] + a1s[i])
    float di = dinv[i];
    float4 hs = *(const float4*)(h + (size_t)i * HID + q * 4);
    float4 g4;
    g4.x = di * (acc.x + hs.x);
    g4.y = di * (acc.y + hs.y);
    g4.z = di * (acc.z + hs.z);
    g4.w = di * (acc.w + hs.w);

    bool act = lane < NCLS;
    int lw = act ? lane : 0;
    float accv = 0.f;
#pragma unroll
    for (int k = 0; k < HID; ++k) {
        float comp = ((k & 3) == 0) ? g4.x : ((k & 3) == 1) ? g4.y
                   : ((k & 3) == 2) ? g4.z : g4.w;
        float gb = __shfl(comp, k >> 2);   // all lanes participate
        accv += gb * w2s[k * NCLS + lw];
    }
    accv += b2s[lw];
    float v = act ? accv : -1e30f;
    for (int d = 32; d >= 1; d >>= 1) v = fmaxf(v, __shfl_xor(v, d));
    float e = act ? __expf(accv - v) : 0.f;
    float s = e;
    for (int d = 32; d >= 1; d >>= 1) s += __shfl_xor(s, d);
    if (act) out[(size_t)i * NCLS + lane] = accv - v - __logf(s);
}

// ---------------- launch ----------------

extern "C" void kernel_launch(void* const* d_in, const int* in_sizes, int n_in,
                              void* d_out, int out_size, void* d_ws, size_t ws_size,
                              hipStream_t stream) {
    const float* x  = (const float*)d_in[0];
    const int*   ei = (const int*)d_in[1];
    const float* W1 = (const float*)d_in[2];
    const float* b1 = (const float*)d_in[3];
    const float* W2 = (const float*)d_in[4];
    const float* b2 = (const float*)d_in[5];

    int N = in_sizes[0] / FEAT;   // 100000
    int E = in_sizes[1] / 2;      // 3200000
    const int* src = ei;
    const int* dst = ei + E;

    char* ws = (char*)d_ws;
    size_t p = 0;
    auto alloc = [&](size_t bytes) -> void* {
        void* r = ws + p;
        p = (p + bytes + 15) & ~(size_t)15;
        return r;
    };
    int*   off  = (int*)alloc((size_t)(N + 1) * 4);
    float* dinv = (float*)alloc((size_t)N * 4);
    int*   csr  = (int*)alloc((size_t)E * 4);
    float* h1   = (float*)alloc((size_t)N * HID * 4);
    float* a1   = (float*)alloc((size_t)N * HID * 4);
    float* pad  = (float*)alloc((size_t)N * HID * 4);  // keeps bpack alias in-bounds
    int*   bcnt = (int*)alloc((size_t)256 * BPAD * 4); // 64B-padded counters
    int*   boff = (int*)alloc((size_t)257 * 4);
    (void)pad;

    // bpack aliases h1/a1/pad (19.2 MB contiguous): consumed by bucket_build
    // before gemm1 writes h1. nbuck*CAPB*4 = 196*18432*4 = 14.45 MB.
    unsigned* bpack = (unsigned*)h1;

    int nbuck = (N + 511) >> 9;               // 196
    int nbin  = (E + CHUNK - 1) / CHUNK;      // 782

    hipMemsetAsync(bcnt, 0, (size_t)256 * BPAD * 4, stream);
    bin2_kernel<<<nbin, 256, 0, stream>>>(src, dst, bcnt, bpack, E);
    bscan_kernel<<<1, 256, 0, stream>>>(bcnt, boff, nbuck);
    bucket_build_kernel<<<nbuck, 256, 0, stream>>>(bpack, boff, off, dinv, csr, N, E);

    gemm1_kernel<<<N / 16, 256, 0, stream>>>(x, W1, dinv, h1, N);
    agg1_kernel<<<(N + 3) / 4, 256, 0, stream>>>(h1, dinv, off, csr, b1, a1, N);
    agg2_final_kernel<<<(N + 3) / 4, 256, 0, stream>>>(a1, dinv, off, csr, W2, b2,
                                                       (float*)d_out, N);
}